// Round 9
// baseline (2296.189 us; speedup 1.0000x reference)
//
#include <hip/hip_runtime.h>
#include <cstdint>
#include <cstddef>

// ---------------------------------------------------------------------------
// GIN forward: h = conv(x; eps0, W1a,W2a) -> conv(h; eps1, W1b,W2b) -> MLP head
// SpMM: per-call CSR build + bf16 multi-edge gather SpMM (fp32 accumulate),
//       emitting PRE-SPLIT hi/lo bf16 planes.
// MLP:  fused Linear->ReLU->Linear, 256-thread blocks, 32-row tiles (R7 shape
//       restored after R8's 64-row regression: occupancy, not W bytes, is the
//       lever). NEW (R9): ring-4 W prefetch + ring-2 A prefetch with unroll-1
//       chunk loops — back-edge pins loads >= 4 tiles ahead of first use so
//       the compiler cannot sink them (R7/R8 emitted distance-1; VGPR 52/64
//       proved the manual pipeline was rematerialized away).
//       Hidden tile in LDS bf16 hi/lo planes (33.8 KB -> 4 blocks/CU).
//       Split-bf16 MFMA (Ah*Wh + Ah*Wl + Al*Wh), fp32-grade accuracy.
// ---------------------------------------------------------------------------

using bf8 = __attribute__((ext_vector_type(8))) short;   // 8 bf16 in 4 VGPRs
using us8 = __attribute__((ext_vector_type(8))) unsigned short;
using f4  = __attribute__((ext_vector_type(4))) float;   // mfma acc

__device__ inline unsigned short f2bf(float f) {          // RNE f32 -> bf16 bits
    unsigned int u = __float_as_uint(f);
    return (unsigned short)((u + 0x7FFFu + ((u >> 16) & 1u)) >> 16);
}
__device__ inline float bf2f(unsigned short h) {
    return __uint_as_float(((unsigned int)h) << 16);
}

__global__ __launch_bounds__(256) void k_zero(int* p, int n) {
    int i = blockIdx.x * 256 + threadIdx.x;
    if (i < n) p[i] = 0;
}

__global__ __launch_bounds__(256) void k_hist(const int* __restrict__ row,
                                              int* __restrict__ cnt, int E) {
    int e = blockIdx.x * 256 + threadIdx.x;
    if (e < E) atomicAdd(&cnt[row[e]], 1);
}

// block scans 1024 elements (256 thr x 4); per-element EXCLUSIVE scan within
// block to base, block total to part[b].
__global__ __launch_bounds__(256) void k_scan1(const int* __restrict__ cnt,
                                               int* __restrict__ base,
                                               int* __restrict__ part, int N) {
    __shared__ int sd[256];
    int t = threadIdx.x;
    int i0 = blockIdx.x * 1024 + t * 4;
    int v0 = (i0 + 0 < N) ? cnt[i0 + 0] : 0;
    int v1 = (i0 + 1 < N) ? cnt[i0 + 1] : 0;
    int v2 = (i0 + 2 < N) ? cnt[i0 + 2] : 0;
    int v3 = (i0 + 3 < N) ? cnt[i0 + 3] : 0;
    int ts = v0 + v1 + v2 + v3;
    sd[t] = ts;
    __syncthreads();
    for (int off = 1; off < 256; off <<= 1) {
        int x = (t >= off) ? sd[t - off] : 0;
        __syncthreads();
        sd[t] += x;
        __syncthreads();
    }
    int excl = sd[t] - ts;
    if (i0 + 0 < N) base[i0 + 0] = excl;
    if (i0 + 1 < N) base[i0 + 1] = excl + v0;
    if (i0 + 2 < N) base[i0 + 2] = excl + v0 + v1;
    if (i0 + 3 < N) base[i0 + 3] = excl + v0 + v1 + v2;
    if (t == 255) part[blockIdx.x] = sd[255];
}

__global__ __launch_bounds__(256) void k_scan2(int* part, int NB) {
    __shared__ int sd[256];
    int t = threadIdx.x;
    int v = (t < NB) ? part[t] : 0;
    sd[t] = v;
    __syncthreads();
    for (int off = 1; off < 256; off <<= 1) {
        int x = (t >= off) ? sd[t - off] : 0;
        __syncthreads();
        sd[t] += x;
        __syncthreads();
    }
    if (t < NB) part[t] = sd[t] - v;
}

__global__ __launch_bounds__(256) void k_scan3(int* __restrict__ base,
                                               int* __restrict__ cursor,
                                               const int* __restrict__ part,
                                               int N, int E) {
    int i = blockIdx.x * 256 + threadIdx.x;
    if (i < N) {
        int b = base[i] + part[i >> 10];
        base[i] = b;
        cursor[i] = b;
    }
    if (i == 0) base[N] = E;
}

__global__ __launch_bounds__(256) void k_scatter(const int* __restrict__ row,
                                                 const int* __restrict__ col,
                                                 const float* __restrict__ vals,
                                                 int* __restrict__ cursor,
                                                 int2* __restrict__ edges, int E) {
    int e = blockIdx.x * 256 + threadIdx.x;
    if (e < E) {
        int p = atomicAdd(&cursor[row[e]], 1);
        edges[p] = make_int2(col[e], __float_as_int(vals[e]));
    }
}

// fp32 -> bf16 cast, 4 elems/thread (n divisible by 4)
__global__ __launch_bounds__(256) void k_cvt(const float* __restrict__ x,
                                             unsigned short* __restrict__ xb, int n) {
    int i = (blockIdx.x * 256 + threadIdx.x) * 4;
    if (i < n) {
        float4 v = *(const float4*)(x + i);
        ushort4 o = {f2bf(v.x), f2bf(v.y), f2bf(v.z), f2bf(v.w)};
        *(ushort4*)(xb + i) = o;
    }
}

// ---------------------------------------------------------------------------
// Wave-per-node CSR SpMM on bf16 rows, fp32 accumulate, fused eps-residual:
//   Y[i] = (1+eps)*Xb[i] + sum_e val[e] * Xb[col[e]]
// Row = D bf16. L = D/8 lanes cover a row at 16B/lane; R = 64/L edges per
// gather instruction. Butterfly-shfl reduce across edge-parts at the end;
// part 0 adds the self term and stores split bf16 hi/lo planes.
// ---------------------------------------------------------------------------
template <int D>
__global__ __launch_bounds__(256) void k_spmm_bf(const int* __restrict__ base,
                                                 const int2* __restrict__ edges,
                                                 const unsigned short* __restrict__ Xb,
                                                 unsigned short* __restrict__ Yhi,
                                                 unsigned short* __restrict__ Ylo,
                                                 const float* __restrict__ epsp,
                                                 int N) {
    constexpr int L = D / 8;    // lanes per row (16 or 32)
    constexpr int R = 64 / L;   // edges per gather instr (4 or 2)
    constexpr int U = 8 / R;    // instrs per inner iter -> 8 edges/iter
    int node = blockIdx.x * 4 + (threadIdx.x >> 6);
    if (node >= N) return;
    const int lane = threadIdx.x & 63;
    const int sub  = lane % L;   // 8-col group within row
    const int part = lane / L;   // which edge of the group
    const float scale = 1.0f + epsp[0];

    float acc[8];
#pragma unroll
    for (int k = 0; k < 8; ++k) acc[k] = 0.0f;

    const int s = base[node];
    const int e = base[node + 1];
    for (int i0 = s; i0 < e; i0 += 64) {
        int rem = e - i0;
        int idx = i0 + (lane < rem ? lane : 0);
        int2 ed = edges[idx];
        int   ci = ed.x;
        float vi = (lane < rem) ? __int_as_float(ed.y) : 0.0f;
        int lim = rem < 64 ? rem : 64;
        for (int j = 0; j < lim; j += 8) {
            int cc[U]; float vv[U];
#pragma unroll
            for (int u = 0; u < U; ++u) {
                int sl = j + u * R + part;      // <= 63 always
                cc[u] = __shfl(ci, sl);
                vv[u] = __shfl(vi, sl);
            }
            us8 g[U];
#pragma unroll
            for (int u = 0; u < U; ++u)
                g[u] = *(const us8*)(Xb + (size_t)cc[u] * D + sub * 8);
#pragma unroll
            for (int u = 0; u < U; ++u)
#pragma unroll
                for (int k = 0; k < 8; ++k)
                    acc[k] = fmaf(bf2f(g[u][k]), vv[u], acc[k]);
        }
    }

    // butterfly-reduce across edge parts (lanes L, 2L, ... apart)
#pragma unroll
    for (int st = L; st < 64; st <<= 1)
#pragma unroll
        for (int k = 0; k < 8; ++k)
            acc[k] += __shfl_xor(acc[k], st);

    if (part == 0) {
        us8 xs = *(const us8*)(Xb + (size_t)node * D + sub * 8);
        us8 hi8, lo8;
#pragma unroll
        for (int k = 0; k < 8; ++k) {
            float o = acc[k] + scale * bf2f(xs[k]);
            unsigned short h = f2bf(o);
            hi8[k] = h;
            lo8[k] = f2bf(o - bf2f(h));
        }
        *(us8*)(Yhi + (size_t)node * D + sub * 8) = hi8;
        *(us8*)(Ylo + (size_t)node * D + sub * 8) = lo8;
    }
}

// ---------------------------------------------------------------------------
// W prep: split W[M][K] fp32 into bf16 hi/lo in exact B-fragment order for
// mfma_f32_16x16x32_bf16:
//   Wf[((c*(M/16)+ct)*64 + lane)*16 + {0..7}=hi, {8..15}=lo]
// where B[k][n]: n = ct*16 + (lane&15), k = c*32 + (lane>>4)*8 + j.
// ---------------------------------------------------------------------------
__device__ inline void wprep_body(const float* __restrict__ W,
                                  short* __restrict__ Wf, int K, int M, int idx) {
    int group = idx >> 9;          // (c, ct)
    int r     = idx & 511;
    int lane  = r >> 3;
    int j     = r & 7;
    int c  = group / (M / 16);
    int ct = group - c * (M / 16);
    int n = ct * 16 + (lane & 15);
    int k = c * 32 + (lane >> 4) * 8 + j;
    float w = W[(size_t)n * K + k];
    unsigned short hi = f2bf(w);
    float res = w - bf2f(hi);
    unsigned short lo = f2bf(res);
    size_t b = (size_t)group * 1024 + (size_t)lane * 16;
    Wf[b + j]     = (short)hi;
    Wf[b + 8 + j] = (short)lo;
}

// one launch preps all six weights; block ranges hardcoded for this problem
__global__ __launch_bounds__(256) void k_wprep_all(
        const float* W1a, short* Q1a, const float* W2a, short* Q2a,
        const float* W1b, short* Q1b, const float* W2b, short* Q2b,
        const float* Wf1, short* Qf1, const float* Wf2, short* Qf2) {
    int b = blockIdx.x;
    const float* W; short* Q; int K, M, lb;
    if      (b < 128)  { W = W1a; Q = Q1a; K = 128; M = 256; lb = b; }
    else if (b < 384)  { W = W2a; Q = Q2a; K = 256; M = 256; lb = b - 128; }
    else if (b < 640)  { W = W1b; Q = Q1b; K = 256; M = 256; lb = b - 384; }
    else if (b < 896)  { W = W2b; Q = Q2b; K = 256; M = 256; lb = b - 640; }
    else if (b < 1152) { W = Wf1; Q = Qf1; K = 256; M = 256; lb = b - 896; }
    else               { W = Wf2; Q = Qf2; K = 256; M = 64;  lb = b - 1152; }
    wprep_body(W, Q, K, M, lb * 256 + threadIdx.x);
}

// ---------------------------------------------------------------------------
// Fused MLP: C = relu(A @ W1^T + b1) @ W2^T + b2    (A: [N,K], hidden 256,
// out MO). Block = 256 thr = 4 waves; tile = 32 rows x all cols.
// ASPLIT: A given as hi/lo bf16 planes (3 MFMAs/tile); else single bf16
//         plane (exact, 2 MFMAs/tile).
// Hidden tile in LDS bf16 hi/lo planes [32][264] (33.8 KB -> 4 blocks/CU).
// Ring-4 W prefetch / ring-2 A prefetch, unroll-1 chunk loops: loads are
// pinned >= 2 chunks (A) / 4 tiles (W) ahead of first use across back-edges.
// OBF: output stored bf16 (RNE), else fp32.
// ---------------------------------------------------------------------------
template <int K, int MO, bool ASPLIT, bool OBF>
__global__ __launch_bounds__(256, 4) void k_mlp(const unsigned short* __restrict__ Ahi,
                                                const unsigned short* __restrict__ Alo,
                                                const short* __restrict__ Wq1,
                                                const float* __restrict__ b1,
                                                const short* __restrict__ Wq2,
                                                const float* __restrict__ b2,
                                                void* __restrict__ Cv, int N) {
    constexpr int MH   = 256;
    constexpr int NCT1 = 4;                     // col-tiles per wave (GEMM1)
    constexpr int NCH1 = K / 32;
    constexpr int NCH2 = MH / 32;               // 8
    constexpr int NCT2 = MO / 64;               // 4 or 1
    constexpr int S1   = NCH1 * NCT1;           // W1 tile sequence length
    constexpr int S2   = NCH2 * NCT2;           // W2 tile sequence length
    constexpr int HS   = 264;                   // LDS row stride in halves
    __shared__ unsigned short Hhi[32 * HS];
    __shared__ unsigned short Hlo[32 * HS];

    const int t    = threadIdx.x;
    const int lane = t & 63;
    const int wq   = t >> 6;
    const int r0   = blockIdx.x * 32;
    const int lm   = lane & 15;
    const int lq   = lane >> 4;
    const int kq   = lq * 8;        // k-offset within chunk for this quad

    // A element offsets (rows clamped -> valid mem, values unused)
    unsigned aoff[2];
#pragma unroll
    for (int rt = 0; rt < 2; ++rt) {
        int gr = r0 + rt * 16 + lm;
        if (gr >= N) gr = N - 1;
        aoff[rt] = (unsigned)gr * K + kq;
    }

    // W1 tile s -> pointer (s = c*NCT1 + ct; tile index = c*16 + wq*NCT1 + ct)
    auto w1tile = [&](int s) {
        int c = s >> 2, ct = s & 3;
        return Wq1 + ((size_t)(c * 16 + wq * NCT1 + ct) * 64 + lane) * 16;
    };

    // ---- GEMM1: A @ W1^T -> acc ----
    f4 acc[2][NCT1];
#pragma unroll
    for (int rt = 0; rt < 2; ++rt)
#pragma unroll
        for (int ct = 0; ct < NCT1; ++ct) acc[rt][ct] = (f4){0.f, 0.f, 0.f, 0.f};

    bf8 ahr[2][2], alr[2][2];       // [slot][rt], ring-2 over k-chunks
#pragma unroll
    for (int p = 0; p < 2; ++p) {
        int cc = (p < NCH1) ? p : NCH1 - 1;
#pragma unroll
        for (int rt = 0; rt < 2; ++rt) {
            ahr[p][rt] = *(const bf8*)(Ahi + aoff[rt] + cc * 32);
            if constexpr (ASPLIT) alr[p][rt] = *(const bf8*)(Alo + aoff[rt] + cc * 32);
        }
    }
    bf8 whr[4], wlr[4];             // ring-4 over W1 tile sequence
#pragma unroll
    for (int p = 0; p < 4; ++p) {
        const short* tp = w1tile(p < S1 ? p : S1 - 1);
        whr[p] = *(const bf8*)(tp);
        wlr[p] = *(const bf8*)(tp + 8);
    }

#pragma unroll 1
    for (int c = 0; c < NCH1; ++c) {
        const int sA = c & 1;
#pragma unroll
        for (int ct = 0; ct < NCT1; ++ct) {
            const int s    = c * NCT1 + ct;
            const int slot = s & 3;
#pragma unroll
            for (int rt = 0; rt < 2; ++rt) {
                acc[rt][ct] = __builtin_amdgcn_mfma_f32_16x16x32_bf16(ahr[sA][rt], whr[slot], acc[rt][ct], 0, 0, 0);
                acc[rt][ct] = __builtin_amdgcn_mfma_f32_16x16x32_bf16(ahr[sA][rt], wlr[slot], acc[rt][ct], 0, 0, 0);
                if constexpr (ASPLIT)
                    acc[rt][ct] = __builtin_amdgcn_mfma_f32_16x16x32_bf16(alr[sA][rt], whr[slot], acc[rt][ct], 0, 0, 0);
            }
            if (s + 4 < S1) {       // refill slot with tile s+4
                const short* tp = w1tile(s + 4);
                whr[slot] = *(const bf8*)(tp);
                wlr[slot] = *(const bf8*)(tp + 8);
            }
        }
        if (c + 2 < NCH1) {         // refill A slot with chunk c+2
#pragma unroll
            for (int rt = 0; rt < 2; ++rt) {
                ahr[sA][rt] = *(const bf8*)(Ahi + aoff[rt] + (c + 2) * 32);
                if constexpr (ASPLIT) alr[sA][rt] = *(const bf8*)(Alo + aoff[rt] + (c + 2) * 32);
            }
        }
    }

    // ---- H = relu(acc + b1), split to bf16 hi/lo -> LDS planes ----
#pragma unroll
    for (int ct = 0; ct < NCT1; ++ct) {
        const int col = wq * 64 + ct * 16 + lm;
        const float bv = b1[col];
#pragma unroll
        for (int rt = 0; rt < 2; ++rt) {
#pragma unroll
            for (int reg = 0; reg < 4; ++reg) {
                int rrow = rt * 16 + lq * 4 + reg;
                float v = acc[rt][ct][reg] + bv;
                v = v > 0.f ? v : 0.f;
                unsigned short h = f2bf(v);
                Hhi[rrow * HS + col] = h;
                Hlo[rrow * HS + col] = f2bf(v - bf2f(h));
            }
        }
    }
    __syncthreads();

    // ---- GEMM2: H @ W2^T + b2 -> C (ring-4 W2; H from LDS) ----
    auto w2tile = [&](int s) {
        int c = s / NCT2, ct = s % NCT2;
        return Wq2 + ((size_t)(c * (MO / 16) + wq * NCT2 + ct) * 64 + lane) * 16;
    };

    f4 acc2[2][NCT2];
#pragma unroll
    for (int rt = 0; rt < 2; ++rt)
#pragma unroll
        for (int ct = 0; ct < NCT2; ++ct) acc2[rt][ct] = (f4){0.f, 0.f, 0.f, 0.f};

    bf8 whr2[4], wlr2[4];
#pragma unroll
    for (int p = 0; p < 4; ++p) {
        const short* tp = w2tile(p < S2 ? p : S2 - 1);
        whr2[p] = *(const bf8*)(tp);
        wlr2[p] = *(const bf8*)(tp + 8);
    }

#pragma unroll 1
    for (int c = 0; c < NCH2; ++c) {
        const int kk = c * 32 + kq;
        bf8 hh[2], hl[2];
#pragma unroll
        for (int rt = 0; rt < 2; ++rt) {
            const int ho = (rt * 16 + lm) * HS + kk;
            hh[rt] = *(const bf8*)(Hhi + ho);
            hl[rt] = *(const bf8*)(Hlo + ho);
        }
#pragma unroll
        for (int ct = 0; ct < NCT2; ++ct) {
            const int s    = c * NCT2 + ct;
            const int slot = s & 3;
#pragma unroll
            for (int rt = 0; rt < 2; ++rt) {
                acc2[rt][ct] = __builtin_amdgcn_mfma_f32_16x16x32_bf16(hh[rt], whr2[slot], acc2[rt][ct], 0, 0, 0);
                acc2[rt][ct] = __builtin_amdgcn_mfma_f32_16x16x32_bf16(hh[rt], wlr2[slot], acc2[rt][ct], 0, 0, 0);
                acc2[rt][ct] = __builtin_amdgcn_mfma_f32_16x16x32_bf16(hl[rt], whr2[slot], acc2[rt][ct], 0, 0, 0);
            }
            if (s + 4 < S2) {
                const short* tp = w2tile(s + 4);
                whr2[slot] = *(const bf8*)(tp);
                wlr2[slot] = *(const bf8*)(tp + 8);
            }
        }
    }

#pragma unroll
    for (int ct = 0; ct < NCT2; ++ct) {
        const int col = wq * (MO / 4) + ct * 16 + lm;
        const float bv = b2[col];
#pragma unroll
        for (int rt = 0; rt < 2; ++rt) {
#pragma unroll
            for (int reg = 0; reg < 4; ++reg) {
                int n = r0 + rt * 16 + lq * 4 + reg;
                if (n < N) {
                    float v = acc2[rt][ct][reg] + bv;
                    if constexpr (OBF)
                        ((unsigned short*)Cv)[(size_t)n * MO + col] = f2bf(v);
                    else
                        ((float*)Cv)[(size_t)n * MO + col] = v;
                }
            }
        }
    }
}

extern "C" void kernel_launch(void* const* d_in, const int* in_sizes, int n_in,
                              void* d_out, int out_size, void* d_ws, size_t ws_size,
                              hipStream_t stream) {
    const float* x    = (const float*)d_in[0];
    const int*   row  = (const int*)d_in[1];
    const int*   col  = (const int*)d_in[2];
    const float* vals = (const float*)d_in[3];
    const float* eps0 = (const float*)d_in[4];
    const float* W1a  = (const float*)d_in[5];
    const float* b1a  = (const float*)d_in[6];
    const float* W2a  = (const float*)d_in[7];
    const float* b2a  = (const float*)d_in[8];
    const float* eps1 = (const float*)d_in[9];
    const float* W1b  = (const float*)d_in[10];
    const float* b1b  = (const float*)d_in[11];
    const float* W2b  = (const float*)d_in[12];
    const float* b2b  = (const float*)d_in[13];
    const float* Wf1  = (const float*)d_in[14];
    const float* bf1  = (const float*)d_in[15];
    const float* Wf2  = (const float*)d_in[16];
    const float* bf2  = (const float*)d_in[17];
    float* out = (float*)d_out;

    const int N = in_sizes[0] / 128;  // 100000
    const int E = in_sizes[1];        // 1600000

    char* w = (char*)d_ws;
    auto alloc = [&](size_t bytes) -> void* {
        void* p = (void*)w;
        w += (bytes + 255) & ~(size_t)255;
        return p;
    };
    unsigned short* Yhi    = (unsigned short*)alloc((size_t)N * 256 * 2); // spmm out hi
    unsigned short* Ylo    = (unsigned short*)alloc((size_t)N * 256 * 2); // spmm out lo
    unsigned short* Hb     = (unsigned short*)alloc((size_t)N * 256 * 2); // bf16 activations
    unsigned short* xb     = (unsigned short*)alloc((size_t)N * 128 * 2); // bf16 input copy
    int*            cnt    = (int*)alloc((size_t)N * 4);
    int*            basep  = (int*)alloc((size_t)(N + 1) * 4);
    int*            cursor = (int*)alloc((size_t)N * 4);
    int*            part   = (int*)alloc(1024);
    int2*           edges  = (int2*)alloc((size_t)E * 8);
    short* Wq1a = (short*)alloc((size_t)128 * 256 * 2 * 2);
    short* Wq2a = (short*)alloc((size_t)256 * 256 * 2 * 2);
    short* Wq1b = (short*)alloc((size_t)256 * 256 * 2 * 2);
    short* Wq2b = (short*)alloc((size_t)256 * 256 * 2 * 2);
    short* Wqf1 = (short*)alloc((size_t)256 * 256 * 2 * 2);
    short* Wqf2 = (short*)alloc((size_t)256 * 64 * 2 * 2);

    // ---- CSR build ----
    k_zero<<<(N + 255) / 256, 256, 0, stream>>>(cnt, N);
    k_hist<<<(E + 255) / 256, 256, 0, stream>>>(row, cnt, E);
    int nb = (N + 1023) / 1024;  // 98
    k_scan1<<<nb, 256, 0, stream>>>(cnt, basep, part, N);
    k_scan2<<<1, 256, 0, stream>>>(part, nb);
    k_scan3<<<(N + 255) / 256, 256, 0, stream>>>(basep, cursor, part, N, E);
    k_scatter<<<(E + 255) / 256, 256, 0, stream>>>(row, col, vals, cursor, edges, E);

    // ---- weight split+swizzle, input bf16 cast ----
    k_wprep_all<<<1216, 256, 0, stream>>>(W1a, Wq1a, W2a, Wq2a, W1b, Wq1b,
                                          W2b, Wq2b, Wf1, Wqf1, Wf2, Wqf2);
    k_cvt<<<(N * 128 / 4 + 255) / 256, 256, 0, stream>>>(x, xb, N * 128);

    const int mlp_grid  = (N + 31) / 32;
    const int spmm_grid = (N + 3) / 4;

    // ---- conv A ----
    k_spmm_bf<128><<<spmm_grid, 256, 0, stream>>>(basep, edges, xb, Yhi, Ylo, eps0, N);
    k_mlp<128, 256, true, true><<<mlp_grid, 256, 0, stream>>>(Yhi, Ylo, Wq1a, b1a, Wq2a, b2a, Hb, N);

    // ---- conv B ----
    k_spmm_bf<256><<<spmm_grid, 256, 0, stream>>>(basep, edges, Hb, Yhi, Ylo, eps1, N);
    k_mlp<256, 256, true, true><<<mlp_grid, 256, 0, stream>>>(Yhi, Ylo, Wq1b, b1b, Wq2b, b2b, Hb, N);

    // ---- head (single-plane bf16 A, exact -> 2 MFMAs in GEMM1) ----
    k_mlp<256, 64, false, false><<<mlp_grid, 256, 0, stream>>>(Hb, nullptr, Wqf1, bf1, Wqf2, bf2, out, N);
}

// Round 10
// 1141.910 us; speedup vs baseline: 2.0108x; 2.0108x over previous
//
#include <hip/hip_runtime.h>
#include <cstdint>
#include <cstddef>

// ---------------------------------------------------------------------------
// GIN forward: h = conv(x; eps0, W1a,W2a) -> conv(h; eps1, W1b,W2b) -> MLP head
// SpMM: per-call CSR build + bf16 multi-edge gather SpMM (fp32 accumulate),
//       emitting PRE-SPLIT hi/lo bf16 planes.
// MLP:  fused Linear->ReLU->Linear, 256-thread blocks, 32-row tiles (R7 code
//       restored; R9's ring prefetch used runtime-indexed register arrays ->
//       scratch spill, MfmaUtil 1.5%). R10: hidden tile stored as a SINGLE
//       bf16 LDS plane (16.9 KB -> 8 blocks/CU, 32 waves/CU) and GEMM2 runs
//       2 MFMAs/tile (Hh*Wh + Hh*Wl; W stays fp32-split, H carries one bf16
//       rounding). launch_bounds(256,8) caps VGPR at 64 (R7 measured 52).
// ---------------------------------------------------------------------------

using bf8 = __attribute__((ext_vector_type(8))) short;   // 8 bf16 in 4 VGPRs
using us8 = __attribute__((ext_vector_type(8))) unsigned short;
using f4  = __attribute__((ext_vector_type(4))) float;   // mfma acc

__device__ inline unsigned short f2bf(float f) {          // RNE f32 -> bf16 bits
    unsigned int u = __float_as_uint(f);
    return (unsigned short)((u + 0x7FFFu + ((u >> 16) & 1u)) >> 16);
}
__device__ inline float bf2f(unsigned short h) {
    return __uint_as_float(((unsigned int)h) << 16);
}

__global__ __launch_bounds__(256) void k_zero(int* p, int n) {
    int i = blockIdx.x * 256 + threadIdx.x;
    if (i < n) p[i] = 0;
}

__global__ __launch_bounds__(256) void k_hist(const int* __restrict__ row,
                                              int* __restrict__ cnt, int E) {
    int e = blockIdx.x * 256 + threadIdx.x;
    if (e < E) atomicAdd(&cnt[row[e]], 1);
}

// block scans 1024 elements (256 thr x 4); per-element EXCLUSIVE scan within
// block to base, block total to part[b].
__global__ __launch_bounds__(256) void k_scan1(const int* __restrict__ cnt,
                                               int* __restrict__ base,
                                               int* __restrict__ part, int N) {
    __shared__ int sd[256];
    int t = threadIdx.x;
    int i0 = blockIdx.x * 1024 + t * 4;
    int v0 = (i0 + 0 < N) ? cnt[i0 + 0] : 0;
    int v1 = (i0 + 1 < N) ? cnt[i0 + 1] : 0;
    int v2 = (i0 + 2 < N) ? cnt[i0 + 2] : 0;
    int v3 = (i0 + 3 < N) ? cnt[i0 + 3] : 0;
    int ts = v0 + v1 + v2 + v3;
    sd[t] = ts;
    __syncthreads();
    for (int off = 1; off < 256; off <<= 1) {
        int x = (t >= off) ? sd[t - off] : 0;
        __syncthreads();
        sd[t] += x;
        __syncthreads();
    }
    int excl = sd[t] - ts;
    if (i0 + 0 < N) base[i0 + 0] = excl;
    if (i0 + 1 < N) base[i0 + 1] = excl + v0;
    if (i0 + 2 < N) base[i0 + 2] = excl + v0 + v1;
    if (i0 + 3 < N) base[i0 + 3] = excl + v0 + v1 + v2;
    if (t == 255) part[blockIdx.x] = sd[255];
}

__global__ __launch_bounds__(256) void k_scan2(int* part, int NB) {
    __shared__ int sd[256];
    int t = threadIdx.x;
    int v = (t < NB) ? part[t] : 0;
    sd[t] = v;
    __syncthreads();
    for (int off = 1; off < 256; off <<= 1) {
        int x = (t >= off) ? sd[t - off] : 0;
        __syncthreads();
        sd[t] += x;
        __syncthreads();
    }
    if (t < NB) part[t] = sd[t] - v;
}

__global__ __launch_bounds__(256) void k_scan3(int* __restrict__ base,
                                               int* __restrict__ cursor,
                                               const int* __restrict__ part,
                                               int N, int E) {
    int i = blockIdx.x * 256 + threadIdx.x;
    if (i < N) {
        int b = base[i] + part[i >> 10];
        base[i] = b;
        cursor[i] = b;
    }
    if (i == 0) base[N] = E;
}

__global__ __launch_bounds__(256) void k_scatter(const int* __restrict__ row,
                                                 const int* __restrict__ col,
                                                 const float* __restrict__ vals,
                                                 int* __restrict__ cursor,
                                                 int2* __restrict__ edges, int E) {
    int e = blockIdx.x * 256 + threadIdx.x;
    if (e < E) {
        int p = atomicAdd(&cursor[row[e]], 1);
        edges[p] = make_int2(col[e], __float_as_int(vals[e]));
    }
}

// fp32 -> bf16 cast, 4 elems/thread (n divisible by 4)
__global__ __launch_bounds__(256) void k_cvt(const float* __restrict__ x,
                                             unsigned short* __restrict__ xb, int n) {
    int i = (blockIdx.x * 256 + threadIdx.x) * 4;
    if (i < n) {
        float4 v = *(const float4*)(x + i);
        ushort4 o = {f2bf(v.x), f2bf(v.y), f2bf(v.z), f2bf(v.w)};
        *(ushort4*)(xb + i) = o;
    }
}

// ---------------------------------------------------------------------------
// Wave-per-node CSR SpMM on bf16 rows, fp32 accumulate, fused eps-residual:
//   Y[i] = (1+eps)*Xb[i] + sum_e val[e] * Xb[col[e]]
// Row = D bf16. L = D/8 lanes cover a row at 16B/lane; R = 64/L edges per
// gather instruction. Butterfly-shfl reduce across edge-parts at the end;
// part 0 adds the self term and stores split bf16 hi/lo planes.
// ---------------------------------------------------------------------------
template <int D>
__global__ __launch_bounds__(256) void k_spmm_bf(const int* __restrict__ base,
                                                 const int2* __restrict__ edges,
                                                 const unsigned short* __restrict__ Xb,
                                                 unsigned short* __restrict__ Yhi,
                                                 unsigned short* __restrict__ Ylo,
                                                 const float* __restrict__ epsp,
                                                 int N) {
    constexpr int L = D / 8;    // lanes per row (16 or 32)
    constexpr int R = 64 / L;   // edges per gather instr (4 or 2)
    constexpr int U = 8 / R;    // instrs per inner iter -> 8 edges/iter
    int node = blockIdx.x * 4 + (threadIdx.x >> 6);
    if (node >= N) return;
    const int lane = threadIdx.x & 63;
    const int sub  = lane % L;   // 8-col group within row
    const int part = lane / L;   // which edge of the group
    const float scale = 1.0f + epsp[0];

    float acc[8];
#pragma unroll
    for (int k = 0; k < 8; ++k) acc[k] = 0.0f;

    const int s = base[node];
    const int e = base[node + 1];
    for (int i0 = s; i0 < e; i0 += 64) {
        int rem = e - i0;
        int idx = i0 + (lane < rem ? lane : 0);
        int2 ed = edges[idx];
        int   ci = ed.x;
        float vi = (lane < rem) ? __int_as_float(ed.y) : 0.0f;
        int lim = rem < 64 ? rem : 64;
        for (int j = 0; j < lim; j += 8) {
            int cc[U]; float vv[U];
#pragma unroll
            for (int u = 0; u < U; ++u) {
                int sl = j + u * R + part;      // <= 63 always
                cc[u] = __shfl(ci, sl);
                vv[u] = __shfl(vi, sl);
            }
            us8 g[U];
#pragma unroll
            for (int u = 0; u < U; ++u)
                g[u] = *(const us8*)(Xb + (size_t)cc[u] * D + sub * 8);
#pragma unroll
            for (int u = 0; u < U; ++u)
#pragma unroll
                for (int k = 0; k < 8; ++k)
                    acc[k] = fmaf(bf2f(g[u][k]), vv[u], acc[k]);
        }
    }

    // butterfly-reduce across edge parts (lanes L, 2L, ... apart)
#pragma unroll
    for (int st = L; st < 64; st <<= 1)
#pragma unroll
        for (int k = 0; k < 8; ++k)
            acc[k] += __shfl_xor(acc[k], st);

    if (part == 0) {
        us8 xs = *(const us8*)(Xb + (size_t)node * D + sub * 8);
        us8 hi8, lo8;
#pragma unroll
        for (int k = 0; k < 8; ++k) {
            float o = acc[k] + scale * bf2f(xs[k]);
            unsigned short h = f2bf(o);
            hi8[k] = h;
            lo8[k] = f2bf(o - bf2f(h));
        }
        *(us8*)(Yhi + (size_t)node * D + sub * 8) = hi8;
        *(us8*)(Ylo + (size_t)node * D + sub * 8) = lo8;
    }
}

// ---------------------------------------------------------------------------
// W prep: split W[M][K] fp32 into bf16 hi/lo in exact B-fragment order for
// mfma_f32_16x16x32_bf16:
//   Wf[((c*(M/16)+ct)*64 + lane)*16 + {0..7}=hi, {8..15}=lo]
// where B[k][n]: n = ct*16 + (lane&15), k = c*32 + (lane>>4)*8 + j.
// ---------------------------------------------------------------------------
__device__ inline void wprep_body(const float* __restrict__ W,
                                  short* __restrict__ Wf, int K, int M, int idx) {
    int group = idx >> 9;          // (c, ct)
    int r     = idx & 511;
    int lane  = r >> 3;
    int j     = r & 7;
    int c  = group / (M / 16);
    int ct = group - c * (M / 16);
    int n = ct * 16 + (lane & 15);
    int k = c * 32 + (lane >> 4) * 8 + j;
    float w = W[(size_t)n * K + k];
    unsigned short hi = f2bf(w);
    float res = w - bf2f(hi);
    unsigned short lo = f2bf(res);
    size_t b = (size_t)group * 1024 + (size_t)lane * 16;
    Wf[b + j]     = (short)hi;
    Wf[b + 8 + j] = (short)lo;
}

// one launch preps all six weights; block ranges hardcoded for this problem
__global__ __launch_bounds__(256) void k_wprep_all(
        const float* W1a, short* Q1a, const float* W2a, short* Q2a,
        const float* W1b, short* Q1b, const float* W2b, short* Q2b,
        const float* Wf1, short* Qf1, const float* Wf2, short* Qf2) {
    int b = blockIdx.x;
    const float* W; short* Q; int K, M, lb;
    if      (b < 128)  { W = W1a; Q = Q1a; K = 128; M = 256; lb = b; }
    else if (b < 384)  { W = W2a; Q = Q2a; K = 256; M = 256; lb = b - 128; }
    else if (b < 640)  { W = W1b; Q = Q1b; K = 256; M = 256; lb = b - 384; }
    else if (b < 896)  { W = W2b; Q = Q2b; K = 256; M = 256; lb = b - 640; }
    else if (b < 1152) { W = Wf1; Q = Qf1; K = 256; M = 256; lb = b - 896; }
    else               { W = Wf2; Q = Qf2; K = 256; M = 64;  lb = b - 1152; }
    wprep_body(W, Q, K, M, lb * 256 + threadIdx.x);
}

// ---------------------------------------------------------------------------
// Fused MLP: C = relu(A @ W1^T + b1) @ W2^T + b2    (A: [N,K], hidden 256,
// out MO). Block = 256 thr = 4 waves; tile = 32 rows x all cols.
// ASPLIT: A given as hi/lo bf16 planes (3 MFMAs/tile); else single bf16
//         plane (exact, 2 MFMAs/tile).
// Hidden tile in LDS as ONE bf16 plane [32][264] (16.9 KB -> 8 blocks/CU);
// GEMM2 = 2 MFMAs/tile (Hh*Wh + Hh*Wl; W fp32-split, H one bf16 rounding).
// K-loop: 1-deep pipeline with named registers (compile-time slots only —
// R9's runtime-indexed rings went to scratch).
// OBF: output stored bf16 (RNE), else fp32.
// ---------------------------------------------------------------------------
template <int K, int MO, bool ASPLIT, bool OBF>
__global__ __launch_bounds__(256, 8) void k_mlp(const unsigned short* __restrict__ Ahi,
                                                const unsigned short* __restrict__ Alo,
                                                const short* __restrict__ Wq1,
                                                const float* __restrict__ b1,
                                                const short* __restrict__ Wq2,
                                                const float* __restrict__ b2,
                                                void* __restrict__ Cv, int N) {
    constexpr int MH   = 256;
    constexpr int NCT1 = MH / 64;   // 4 col-tiles per wave (GEMM1)
    constexpr int NCH1 = K / 32;
    constexpr int NCH2 = MH / 32;   // 8
    constexpr int NCT2 = MO / 64;   // 4 or 1
    constexpr int HS   = 264;       // LDS row stride in halves (132 words)
    __shared__ unsigned short Hhi[32 * HS];

    const int t    = threadIdx.x;
    const int lane = t & 63;
    const int wq   = t >> 6;
    const int r0   = blockIdx.x * 32;
    const int lm   = lane & 15;
    const int lq   = lane >> 4;
    const int kq   = lq * 8;        // k-offset within chunk for this quad

    // A row pointers (fixed across k; clamp: valid mem, clamped rows unused)
    const unsigned short* aph[2];
    const unsigned short* apl[2];
#pragma unroll
    for (int rt = 0; rt < 2; ++rt) {
        int gr = r0 + rt * 16 + lm;
        if (gr >= N) gr = N - 1;
        aph[rt] = Ahi + (size_t)gr * K + kq;
        if constexpr (ASPLIT) apl[rt] = Alo + (size_t)gr * K + kq;
    }

    // ---- GEMM1: A @ W1^T -> acc (pipelined) ----
    f4 acc[2][NCT1];
#pragma unroll
    for (int rt = 0; rt < 2; ++rt)
#pragma unroll
        for (int ct = 0; ct < NCT1; ++ct) acc[rt][ct] = (f4){0.f, 0.f, 0.f, 0.f};

    bf8 ah[2], al[2];
#pragma unroll
    for (int rt = 0; rt < 2; ++rt) {
        ah[rt] = *(const bf8*)(aph[rt]);
        if constexpr (ASPLIT) al[rt] = *(const bf8*)(apl[rt]);
    }
    // W pointer walk: within c: +1024 shorts per ct; c->c+1: +(16-(NCT1-1))*1024
    const short* wp = Wq1 + ((size_t)(wq * NCT1) * 64 + lane) * 16;
    bf8 wh = *(const bf8*)(wp);
    bf8 wl = *(const bf8*)(wp + 8);

#pragma unroll 1
    for (int c = 0; c < NCH1; ++c) {
        bf8 ahn[2], aln[2];
        if (c + 1 < NCH1) {
#pragma unroll
            for (int rt = 0; rt < 2; ++rt) {
                ahn[rt] = *(const bf8*)(aph[rt] + (c + 1) * 32);
                if constexpr (ASPLIT) aln[rt] = *(const bf8*)(apl[rt] + (c + 1) * 32);
            }
        }
#pragma unroll
        for (int ct = 0; ct < NCT1; ++ct) {
            const short* wpn = wp + ((ct + 1 < NCT1) ? 1024
                                                     : (size_t)(16 - (NCT1 - 1)) * 1024);
            bf8 whn, wln;
            if (c * NCT1 + ct + 1 < NCH1 * NCT1) {
                whn = *(const bf8*)(wpn);
                wln = *(const bf8*)(wpn + 8);
            }
#pragma unroll
            for (int rt = 0; rt < 2; ++rt) {
                acc[rt][ct] = __builtin_amdgcn_mfma_f32_16x16x32_bf16(ah[rt], wh, acc[rt][ct], 0, 0, 0);
                acc[rt][ct] = __builtin_amdgcn_mfma_f32_16x16x32_bf16(ah[rt], wl, acc[rt][ct], 0, 0, 0);
                if constexpr (ASPLIT)
                    acc[rt][ct] = __builtin_amdgcn_mfma_f32_16x16x32_bf16(al[rt], wh, acc[rt][ct], 0, 0, 0);
            }
            wh = whn; wl = wln; wp = wpn;
        }
#pragma unroll
        for (int rt = 0; rt < 2; ++rt) {
            ah[rt] = ahn[rt];
            if constexpr (ASPLIT) al[rt] = aln[rt];
        }
    }

    // ---- H = relu(acc + b1) -> single bf16 LDS plane ----
#pragma unroll
    for (int ct = 0; ct < NCT1; ++ct) {
        const int col = wq * 64 + ct * 16 + lm;
        const float bv = b1[col];
#pragma unroll
        for (int rt = 0; rt < 2; ++rt) {
#pragma unroll
            for (int reg = 0; reg < 4; ++reg) {
                int rrow = rt * 16 + lq * 4 + reg;
                float v = acc[rt][ct][reg] + bv;
                v = v > 0.f ? v : 0.f;
                Hhi[rrow * HS + col] = f2bf(v);
            }
        }
    }
    __syncthreads();

    // ---- GEMM2: H @ W2^T + b2 -> C (W pipelined; H from LDS; 2 MFMAs) ----
    f4 acc2[2][NCT2];
#pragma unroll
    for (int rt = 0; rt < 2; ++rt)
#pragma unroll
        for (int ct = 0; ct < NCT2; ++ct) acc2[rt][ct] = (f4){0.f, 0.f, 0.f, 0.f};

    const short* wp2 = Wq2 + ((size_t)(wq * NCT2) * 64 + lane) * 16;
    bf8 wh2 = *(const bf8*)(wp2);
    bf8 wl2 = *(const bf8*)(wp2 + 8);

#pragma unroll 1
    for (int c = 0; c < NCH2; ++c) {
        const int kk = c * 32 + kq;
        bf8 hh[2];
#pragma unroll
        for (int rt = 0; rt < 2; ++rt)
            hh[rt] = *(const bf8*)(Hhi + (rt * 16 + lm) * HS + kk);
#pragma unroll
        for (int ct = 0; ct < NCT2; ++ct) {
            const short* wpn = wp2 + ((ct + 1 < NCT2) ? 1024
                                                      : (size_t)(MO / 16 - (NCT2 - 1)) * 1024);
            bf8 whn, wln;
            if (c * NCT2 + ct + 1 < NCH2 * NCT2) {
                whn = *(const bf8*)(wpn);
                wln = *(const bf8*)(wpn + 8);
            }
#pragma unroll
            for (int rt = 0; rt < 2; ++rt) {
                acc2[rt][ct] = __builtin_amdgcn_mfma_f32_16x16x32_bf16(hh[rt], wh2, acc2[rt][ct], 0, 0, 0);
                acc2[rt][ct] = __builtin_amdgcn_mfma_f32_16x16x32_bf16(hh[rt], wl2, acc2[rt][ct], 0, 0, 0);
            }
            wh2 = whn; wl2 = wln; wp2 = wpn;
        }
    }

#pragma unroll
    for (int ct = 0; ct < NCT2; ++ct) {
        const int col = wq * (MO / 4) + ct * 16 + lm;
        const float bv = b2[col];
#pragma unroll
        for (int rt = 0; rt < 2; ++rt) {
#pragma unroll
            for (int reg = 0; reg < 4; ++reg) {
                int n = r0 + rt * 16 + lq * 4 + reg;
                if (n < N) {
                    float v = acc2[rt][ct][reg] + bv;
                    if constexpr (OBF)
                        ((unsigned short*)Cv)[(size_t)n * MO + col] = f2bf(v);
                    else
                        ((float*)Cv)[(size_t)n * MO + col] = v;
                }
            }
        }
    }
}

extern "C" void kernel_launch(void* const* d_in, const int* in_sizes, int n_in,
                              void* d_out, int out_size, void* d_ws, size_t ws_size,
                              hipStream_t stream) {
    const float* x    = (const float*)d_in[0];
    const int*   row  = (const int*)d_in[1];
    const int*   col  = (const int*)d_in[2];
    const float* vals = (const float*)d_in[3];
    const float* eps0 = (const float*)d_in[4];
    const float* W1a  = (const float*)d_in[5];
    const float* b1a  = (const float*)d_in[6];
    const float* W2a  = (const float*)d_in[7];
    const float* b2a  = (const float*)d_in[8];
    const float* eps1 = (const float*)d_in[9];
    const float* W1b  = (const float*)d_in[10];
    const float* b1b  = (const float*)d_in[11];
    const float* W2b  = (const float*)d_in[12];
    const float* b2b  = (const float*)d_in[13];
    const float* Wf1  = (const float*)d_in[14];
    const float* bf1  = (const float*)d_in[15];
    const float* Wf2  = (const float*)d_in[16];
    const float* bf2  = (const float*)d_in[17];
    float* out = (float*)d_out;

    const int N = in_sizes[0] / 128;  // 100000
    const int E = in_sizes[1];        // 1600000

    char* w = (char*)d_ws;
    auto alloc = [&](size_t bytes) -> void* {
        void* p = (void*)w;
        w += (bytes + 255) & ~(size_t)255;
        return p;
    };
    unsigned short* Yhi    = (unsigned short*)alloc((size_t)N * 256 * 2); // spmm out hi
    unsigned short* Ylo    = (unsigned short*)alloc((size_t)N * 256 * 2); // spmm out lo
    unsigned short* Hb     = (unsigned short*)alloc((size_t)N * 256 * 2); // bf16 activations
    unsigned short* xb     = (unsigned short*)alloc((size_t)N * 128 * 2); // bf16 input copy
    int*            cnt    = (int*)alloc((size_t)N * 4);
    int*            basep  = (int*)alloc((size_t)(N + 1) * 4);
    int*            cursor = (int*)alloc((size_t)N * 4);
    int*            part   = (int*)alloc(1024);
    int2*           edges  = (int2*)alloc((size_t)E * 8);
    short* Wq1a = (short*)alloc((size_t)128 * 256 * 2 * 2);
    short* Wq2a = (short*)alloc((size_t)256 * 256 * 2 * 2);
    short* Wq1b = (short*)alloc((size_t)256 * 256 * 2 * 2);
    short* Wq2b = (short*)alloc((size_t)256 * 256 * 2 * 2);
    short* Wqf1 = (short*)alloc((size_t)256 * 256 * 2 * 2);
    short* Wqf2 = (short*)alloc((size_t)256 * 64 * 2 * 2);

    // ---- CSR build ----
    k_zero<<<(N + 255) / 256, 256, 0, stream>>>(cnt, N);
    k_hist<<<(E + 255) / 256, 256, 0, stream>>>(row, cnt, E);
    int nb = (N + 1023) / 1024;  // 98
    k_scan1<<<nb, 256, 0, stream>>>(cnt, basep, part, N);
    k_scan2<<<1, 256, 0, stream>>>(part, nb);
    k_scan3<<<(N + 255) / 256, 256, 0, stream>>>(basep, cursor, part, N, E);
    k_scatter<<<(E + 255) / 256, 256, 0, stream>>>(row, col, vals, cursor, edges, E);

    // ---- weight split+swizzle, input bf16 cast ----
    k_wprep_all<<<1216, 256, 0, stream>>>(W1a, Wq1a, W2a, Wq2a, W1b, Wq1b,
                                          W2b, Wq2b, Wf1, Wqf1, Wf2, Wqf2);
    k_cvt<<<(N * 128 / 4 + 255) / 256, 256, 0, stream>>>(x, xb, N * 128);

    const int mlp_grid  = (N + 31) / 32;
    const int spmm_grid = (N + 3) / 4;

    // ---- conv A ----
    k_spmm_bf<128><<<spmm_grid, 256, 0, stream>>>(basep, edges, xb, Yhi, Ylo, eps0, N);
    k_mlp<128, 256, true, true><<<mlp_grid, 256, 0, stream>>>(Yhi, Ylo, Wq1a, b1a, Wq2a, b2a, Hb, N);

    // ---- conv B ----
    k_spmm_bf<256><<<spmm_grid, 256, 0, stream>>>(basep, edges, Hb, Yhi, Ylo, eps1, N);
    k_mlp<256, 256, true, true><<<mlp_grid, 256, 0, stream>>>(Yhi, Ylo, Wq1b, b1b, Wq2b, b2b, Hb, N);

    // ---- head (single-plane bf16 A, exact -> 2 MFMAs in GEMM1) ----
    k_mlp<256, 64, false, false><<<mlp_grid, 256, 0, stream>>>(Hb, nullptr, Wqf1, bf1, Wqf2, bf2, out, N);
}

// Round 11
// 755.698 us; speedup vs baseline: 3.0385x; 1.5111x over previous
//
#include <hip/hip_runtime.h>
#include <cstdint>
#include <cstddef>

// ---------------------------------------------------------------------------
// GIN forward: h = conv(x; eps0, W1a,W2a) -> conv(h; eps1, W1b,W2b) -> MLP head
// SpMM: per-call CSR build + bf16 multi-edge gather SpMM (fp32 accumulate),
//       emitting PRE-SPLIT hi/lo bf16 planes.
// MLP:  fused Linear->ReLU->Linear, 256-thread blocks, 32-row tiles.
//       Hidden tile = ONE bf16 LDS plane (16.9 KB); GEMM2 = 2 MFMAs/tile.
//       launch_bounds(256,4): R10's (256,8) capped VGPR at 64 -> accumulator
//       spill to scratch (WRITE_SIZE 85->749 MB, MfmaUtil 7.9%). With the
//       128 cap the kernel sits at ~52-64 VGPR and reaches 8 blocks/CU via
//       the HW limits (VGPR 512/52>8, LDS 160/16.9>8) with zero spill.
//       Split-bf16 MFMA (Ah*Wh + Ah*Wl + Al*Wh) in GEMM1, fp32-grade.
// ---------------------------------------------------------------------------

using bf8 = __attribute__((ext_vector_type(8))) short;   // 8 bf16 in 4 VGPRs
using us8 = __attribute__((ext_vector_type(8))) unsigned short;
using f4  = __attribute__((ext_vector_type(4))) float;   // mfma acc

__device__ inline unsigned short f2bf(float f) {          // RNE f32 -> bf16 bits
    unsigned int u = __float_as_uint(f);
    return (unsigned short)((u + 0x7FFFu + ((u >> 16) & 1u)) >> 16);
}
__device__ inline float bf2f(unsigned short h) {
    return __uint_as_float(((unsigned int)h) << 16);
}

__global__ __launch_bounds__(256) void k_zero(int* p, int n) {
    int i = blockIdx.x * 256 + threadIdx.x;
    if (i < n) p[i] = 0;
}

__global__ __launch_bounds__(256) void k_hist(const int* __restrict__ row,
                                              int* __restrict__ cnt, int E) {
    int e = blockIdx.x * 256 + threadIdx.x;
    if (e < E) atomicAdd(&cnt[row[e]], 1);
}

// block scans 1024 elements (256 thr x 4); per-element EXCLUSIVE scan within
// block to base, block total to part[b].
__global__ __launch_bounds__(256) void k_scan1(const int* __restrict__ cnt,
                                               int* __restrict__ base,
                                               int* __restrict__ part, int N) {
    __shared__ int sd[256];
    int t = threadIdx.x;
    int i0 = blockIdx.x * 1024 + t * 4;
    int v0 = (i0 + 0 < N) ? cnt[i0 + 0] : 0;
    int v1 = (i0 + 1 < N) ? cnt[i0 + 1] : 0;
    int v2 = (i0 + 2 < N) ? cnt[i0 + 2] : 0;
    int v3 = (i0 + 3 < N) ? cnt[i0 + 3] : 0;
    int ts = v0 + v1 + v2 + v3;
    sd[t] = ts;
    __syncthreads();
    for (int off = 1; off < 256; off <<= 1) {
        int x = (t >= off) ? sd[t - off] : 0;
        __syncthreads();
        sd[t] += x;
        __syncthreads();
    }
    int excl = sd[t] - ts;
    if (i0 + 0 < N) base[i0 + 0] = excl;
    if (i0 + 1 < N) base[i0 + 1] = excl + v0;
    if (i0 + 2 < N) base[i0 + 2] = excl + v0 + v1;
    if (i0 + 3 < N) base[i0 + 3] = excl + v0 + v1 + v2;
    if (t == 255) part[blockIdx.x] = sd[255];
}

__global__ __launch_bounds__(256) void k_scan2(int* part, int NB) {
    __shared__ int sd[256];
    int t = threadIdx.x;
    int v = (t < NB) ? part[t] : 0;
    sd[t] = v;
    __syncthreads();
    for (int off = 1; off < 256; off <<= 1) {
        int x = (t >= off) ? sd[t - off] : 0;
        __syncthreads();
        sd[t] += x;
        __syncthreads();
    }
    if (t < NB) part[t] = sd[t] - v;
}

__global__ __launch_bounds__(256) void k_scan3(int* __restrict__ base,
                                               int* __restrict__ cursor,
                                               const int* __restrict__ part,
                                               int N, int E) {
    int i = blockIdx.x * 256 + threadIdx.x;
    if (i < N) {
        int b = base[i] + part[i >> 10];
        base[i] = b;
        cursor[i] = b;
    }
    if (i == 0) base[N] = E;
}

__global__ __launch_bounds__(256) void k_scatter(const int* __restrict__ row,
                                                 const int* __restrict__ col,
                                                 const float* __restrict__ vals,
                                                 int* __restrict__ cursor,
                                                 int2* __restrict__ edges, int E) {
    int e = blockIdx.x * 256 + threadIdx.x;
    if (e < E) {
        int p = atomicAdd(&cursor[row[e]], 1);
        edges[p] = make_int2(col[e], __float_as_int(vals[e]));
    }
}

// fp32 -> bf16 cast, 4 elems/thread (n divisible by 4)
__global__ __launch_bounds__(256) void k_cvt(const float* __restrict__ x,
                                             unsigned short* __restrict__ xb, int n) {
    int i = (blockIdx.x * 256 + threadIdx.x) * 4;
    if (i < n) {
        float4 v = *(const float4*)(x + i);
        ushort4 o = {f2bf(v.x), f2bf(v.y), f2bf(v.z), f2bf(v.w)};
        *(ushort4*)(xb + i) = o;
    }
}

// ---------------------------------------------------------------------------
// Wave-per-node CSR SpMM on bf16 rows, fp32 accumulate, fused eps-residual:
//   Y[i] = (1+eps)*Xb[i] + sum_e val[e] * Xb[col[e]]
// Row = D bf16. L = D/8 lanes cover a row at 16B/lane; R = 64/L edges per
// gather instruction. Butterfly-shfl reduce across edge-parts at the end;
// part 0 adds the self term and stores split bf16 hi/lo planes.
// ---------------------------------------------------------------------------
template <int D>
__global__ __launch_bounds__(256) void k_spmm_bf(const int* __restrict__ base,
                                                 const int2* __restrict__ edges,
                                                 const unsigned short* __restrict__ Xb,
                                                 unsigned short* __restrict__ Yhi,
                                                 unsigned short* __restrict__ Ylo,
                                                 const float* __restrict__ epsp,
                                                 int N) {
    constexpr int L = D / 8;    // lanes per row (16 or 32)
    constexpr int R = 64 / L;   // edges per gather instr (4 or 2)
    constexpr int U = 8 / R;    // instrs per inner iter -> 8 edges/iter
    int node = blockIdx.x * 4 + (threadIdx.x >> 6);
    if (node >= N) return;
    const int lane = threadIdx.x & 63;
    const int sub  = lane % L;   // 8-col group within row
    const int part = lane / L;   // which edge of the group
    const float scale = 1.0f + epsp[0];

    float acc[8];
#pragma unroll
    for (int k = 0; k < 8; ++k) acc[k] = 0.0f;

    const int s = base[node];
    const int e = base[node + 1];
    for (int i0 = s; i0 < e; i0 += 64) {
        int rem = e - i0;
        int idx = i0 + (lane < rem ? lane : 0);
        int2 ed = edges[idx];
        int   ci = ed.x;
        float vi = (lane < rem) ? __int_as_float(ed.y) : 0.0f;
        int lim = rem < 64 ? rem : 64;
        for (int j = 0; j < lim; j += 8) {
            int cc[U]; float vv[U];
#pragma unroll
            for (int u = 0; u < U; ++u) {
                int sl = j + u * R + part;      // <= 63 always
                cc[u] = __shfl(ci, sl);
                vv[u] = __shfl(vi, sl);
            }
            us8 g[U];
#pragma unroll
            for (int u = 0; u < U; ++u)
                g[u] = *(const us8*)(Xb + (size_t)cc[u] * D + sub * 8);
#pragma unroll
            for (int u = 0; u < U; ++u)
#pragma unroll
                for (int k = 0; k < 8; ++k)
                    acc[k] = fmaf(bf2f(g[u][k]), vv[u], acc[k]);
        }
    }

    // butterfly-reduce across edge parts (lanes L, 2L, ... apart)
#pragma unroll
    for (int st = L; st < 64; st <<= 1)
#pragma unroll
        for (int k = 0; k < 8; ++k)
            acc[k] += __shfl_xor(acc[k], st);

    if (part == 0) {
        us8 xs = *(const us8*)(Xb + (size_t)node * D + sub * 8);
        us8 hi8, lo8;
#pragma unroll
        for (int k = 0; k < 8; ++k) {
            float o = acc[k] + scale * bf2f(xs[k]);
            unsigned short h = f2bf(o);
            hi8[k] = h;
            lo8[k] = f2bf(o - bf2f(h));
        }
        *(us8*)(Yhi + (size_t)node * D + sub * 8) = hi8;
        *(us8*)(Ylo + (size_t)node * D + sub * 8) = lo8;
    }
}

// ---------------------------------------------------------------------------
// W prep: split W[M][K] fp32 into bf16 hi/lo in exact B-fragment order for
// mfma_f32_16x16x32_bf16:
//   Wf[((c*(M/16)+ct)*64 + lane)*16 + {0..7}=hi, {8..15}=lo]
// where B[k][n]: n = ct*16 + (lane&15), k = c*32 + (lane>>4)*8 + j.
// ---------------------------------------------------------------------------
__device__ inline void wprep_body(const float* __restrict__ W,
                                  short* __restrict__ Wf, int K, int M, int idx) {
    int group = idx >> 9;          // (c, ct)
    int r     = idx & 511;
    int lane  = r >> 3;
    int j     = r & 7;
    int c  = group / (M / 16);
    int ct = group - c * (M / 16);
    int n = ct * 16 + (lane & 15);
    int k = c * 32 + (lane >> 4) * 8 + j;
    float w = W[(size_t)n * K + k];
    unsigned short hi = f2bf(w);
    float res = w - bf2f(hi);
    unsigned short lo = f2bf(res);
    size_t b = (size_t)group * 1024 + (size_t)lane * 16;
    Wf[b + j]     = (short)hi;
    Wf[b + 8 + j] = (short)lo;
}

// one launch preps all six weights; block ranges hardcoded for this problem
__global__ __launch_bounds__(256) void k_wprep_all(
        const float* W1a, short* Q1a, const float* W2a, short* Q2a,
        const float* W1b, short* Q1b, const float* W2b, short* Q2b,
        const float* Wf1, short* Qf1, const float* Wf2, short* Qf2) {
    int b = blockIdx.x;
    const float* W; short* Q; int K, M, lb;
    if      (b < 128)  { W = W1a; Q = Q1a; K = 128; M = 256; lb = b; }
    else if (b < 384)  { W = W2a; Q = Q2a; K = 256; M = 256; lb = b - 128; }
    else if (b < 640)  { W = W1b; Q = Q1b; K = 256; M = 256; lb = b - 384; }
    else if (b < 896)  { W = W2b; Q = Q2b; K = 256; M = 256; lb = b - 640; }
    else if (b < 1152) { W = Wf1; Q = Qf1; K = 256; M = 256; lb = b - 896; }
    else               { W = Wf2; Q = Qf2; K = 256; M = 64;  lb = b - 1152; }
    wprep_body(W, Q, K, M, lb * 256 + threadIdx.x);
}

// ---------------------------------------------------------------------------
// Fused MLP: C = relu(A @ W1^T + b1) @ W2^T + b2    (A: [N,K], hidden 256,
// out MO). Block = 256 thr = 4 waves; tile = 32 rows x all cols.
// ASPLIT: A given as hi/lo bf16 planes (3 MFMAs/tile); else single bf16
//         plane (exact, 2 MFMAs/tile).
// Hidden tile in LDS as ONE bf16 plane [32][264] (16.9 KB; with ~52-64 VGPR
// the HW limits give 8 blocks/CU). GEMM2 = 2 MFMAs/tile (Hh*Wh + Hh*Wl).
// K-loop: 1-deep pipeline with named registers (compile-time slots only).
// OBF: output stored bf16 (RNE), else fp32.
// ---------------------------------------------------------------------------
template <int K, int MO, bool ASPLIT, bool OBF>
__global__ __launch_bounds__(256, 4) void k_mlp(const unsigned short* __restrict__ Ahi,
                                                const unsigned short* __restrict__ Alo,
                                                const short* __restrict__ Wq1,
                                                const float* __restrict__ b1,
                                                const short* __restrict__ Wq2,
                                                const float* __restrict__ b2,
                                                void* __restrict__ Cv, int N) {
    constexpr int MH   = 256;
    constexpr int NCT1 = MH / 64;   // 4 col-tiles per wave (GEMM1)
    constexpr int NCH1 = K / 32;
    constexpr int NCH2 = MH / 32;   // 8
    constexpr int NCT2 = MO / 64;   // 4 or 1
    constexpr int HS   = 264;       // LDS row stride in halves (132 words)
    __shared__ unsigned short Hhi[32 * HS];

    const int t    = threadIdx.x;
    const int lane = t & 63;
    const int wq   = t >> 6;
    const int r0   = blockIdx.x * 32;
    const int lm   = lane & 15;
    const int lq   = lane >> 4;
    const int kq   = lq * 8;        // k-offset within chunk for this quad

    // A row pointers (fixed across k; clamp: valid mem, clamped rows unused)
    const unsigned short* aph[2];
    const unsigned short* apl[2];
#pragma unroll
    for (int rt = 0; rt < 2; ++rt) {
        int gr = r0 + rt * 16 + lm;
        if (gr >= N) gr = N - 1;
        aph[rt] = Ahi + (size_t)gr * K + kq;
        if constexpr (ASPLIT) apl[rt] = Alo + (size_t)gr * K + kq;
    }

    // ---- GEMM1: A @ W1^T -> acc (pipelined) ----
    f4 acc[2][NCT1];
#pragma unroll
    for (int rt = 0; rt < 2; ++rt)
#pragma unroll
        for (int ct = 0; ct < NCT1; ++ct) acc[rt][ct] = (f4){0.f, 0.f, 0.f, 0.f};

    bf8 ah[2], al[2];
#pragma unroll
    for (int rt = 0; rt < 2; ++rt) {
        ah[rt] = *(const bf8*)(aph[rt]);
        if constexpr (ASPLIT) al[rt] = *(const bf8*)(apl[rt]);
    }
    // W pointer walk: within c: +1024 shorts per ct; c->c+1: +(16-(NCT1-1))*1024
    const short* wp = Wq1 + ((size_t)(wq * NCT1) * 64 + lane) * 16;
    bf8 wh = *(const bf8*)(wp);
    bf8 wl = *(const bf8*)(wp + 8);

#pragma unroll 1
    for (int c = 0; c < NCH1; ++c) {
        bf8 ahn[2], aln[2];
        if (c + 1 < NCH1) {
#pragma unroll
            for (int rt = 0; rt < 2; ++rt) {
                ahn[rt] = *(const bf8*)(aph[rt] + (c + 1) * 32);
                if constexpr (ASPLIT) aln[rt] = *(const bf8*)(apl[rt] + (c + 1) * 32);
            }
        }
#pragma unroll
        for (int ct = 0; ct < NCT1; ++ct) {
            const short* wpn = wp + ((ct + 1 < NCT1) ? 1024
                                                     : (size_t)(16 - (NCT1 - 1)) * 1024);
            bf8 whn, wln;
            if (c * NCT1 + ct + 1 < NCH1 * NCT1) {
                whn = *(const bf8*)(wpn);
                wln = *(const bf8*)(wpn + 8);
            }
#pragma unroll
            for (int rt = 0; rt < 2; ++rt) {
                acc[rt][ct] = __builtin_amdgcn_mfma_f32_16x16x32_bf16(ah[rt], wh, acc[rt][ct], 0, 0, 0);
                acc[rt][ct] = __builtin_amdgcn_mfma_f32_16x16x32_bf16(ah[rt], wl, acc[rt][ct], 0, 0, 0);
                if constexpr (ASPLIT)
                    acc[rt][ct] = __builtin_amdgcn_mfma_f32_16x16x32_bf16(al[rt], wh, acc[rt][ct], 0, 0, 0);
            }
            wh = whn; wl = wln; wp = wpn;
        }
#pragma unroll
        for (int rt = 0; rt < 2; ++rt) {
            ah[rt] = ahn[rt];
            if constexpr (ASPLIT) al[rt] = aln[rt];
        }
    }

    // ---- H = relu(acc + b1) -> single bf16 LDS plane ----
#pragma unroll
    for (int ct = 0; ct < NCT1; ++ct) {
        const int col = wq * 64 + ct * 16 + lm;
        const float bv = b1[col];
#pragma unroll
        for (int rt = 0; rt < 2; ++rt) {
#pragma unroll
            for (int reg = 0; reg < 4; ++reg) {
                int rrow = rt * 16 + lq * 4 + reg;
                float v = acc[rt][ct][reg] + bv;
                v = v > 0.f ? v : 0.f;
                Hhi[rrow * HS + col] = f2bf(v);
            }
        }
    }
    __syncthreads();

    // ---- GEMM2: H @ W2^T + b2 -> C (W pipelined; H from LDS; 2 MFMAs) ----
    f4 acc2[2][NCT2];
#pragma unroll
    for (int rt = 0; rt < 2; ++rt)
#pragma unroll
        for (int ct = 0; ct < NCT2; ++ct) acc2[rt][ct] = (f4){0.f, 0.f, 0.f, 0.f};

    const short* wp2 = Wq2 + ((size_t)(wq * NCT2) * 64 + lane) * 16;
    bf8 wh2 = *(const bf8*)(wp2);
    bf8 wl2 = *(const bf8*)(wp2 + 8);

#pragma unroll 1
    for (int c = 0; c < NCH2; ++c) {
        const int kk = c * 32 + kq;
        bf8 hh[2];
#pragma unroll
        for (int rt = 0; rt < 2; ++rt)
            hh[rt] = *(const bf8*)(Hhi + (rt * 16 + lm) * HS + kk);
#pragma unroll
        for (int ct = 0; ct < NCT2; ++ct) {
            const short* wpn = wp2 + ((ct + 1 < NCT2) ? 1024
                                                      : (size_t)(MO / 16 - (NCT2 - 1)) * 1024);
            bf8 whn, wln;
            if (c * NCT2 + ct + 1 < NCH2 * NCT2) {
                whn = *(const bf8*)(wpn);
                wln = *(const bf8*)(wpn + 8);
            }
#pragma unroll
            for (int rt = 0; rt < 2; ++rt) {
                acc2[rt][ct] = __builtin_amdgcn_mfma_f32_16x16x32_bf16(hh[rt], wh2, acc2[rt][ct], 0, 0, 0);
                acc2[rt][ct] = __builtin_amdgcn_mfma_f32_16x16x32_bf16(hh[rt], wl2, acc2[rt][ct], 0, 0, 0);
            }
            wh2 = whn; wl2 = wln; wp2 = wpn;
        }
    }

#pragma unroll
    for (int ct = 0; ct < NCT2; ++ct) {
        const int col = wq * (MO / 4) + ct * 16 + lm;
        const float bv = b2[col];
#pragma unroll
        for (int rt = 0; rt < 2; ++rt) {
#pragma unroll
            for (int reg = 0; reg < 4; ++reg) {
                int n = r0 + rt * 16 + lq * 4 + reg;
                if (n < N) {
                    float v = acc2[rt][ct][reg] + bv;
                    if constexpr (OBF)
                        ((unsigned short*)Cv)[(size_t)n * MO + col] = f2bf(v);
                    else
                        ((float*)Cv)[(size_t)n * MO + col] = v;
                }
            }
        }
    }
}

extern "C" void kernel_launch(void* const* d_in, const int* in_sizes, int n_in,
                              void* d_out, int out_size, void* d_ws, size_t ws_size,
                              hipStream_t stream) {
    const float* x    = (const float*)d_in[0];
    const int*   row  = (const int*)d_in[1];
    const int*   col  = (const int*)d_in[2];
    const float* vals = (const float*)d_in[3];
    const float* eps0 = (const float*)d_in[4];
    const float* W1a  = (const float*)d_in[5];
    const float* b1a  = (const float*)d_in[6];
    const float* W2a  = (const float*)d_in[7];
    const float* b2a  = (const float*)d_in[8];
    const float* eps1 = (const float*)d_in[9];
    const float* W1b  = (const float*)d_in[10];
    const float* b1b  = (const float*)d_in[11];
    const float* W2b  = (const float*)d_in[12];
    const float* b2b  = (const float*)d_in[13];
    const float* Wf1  = (const float*)d_in[14];
    const float* bf1  = (const float*)d_in[15];
    const float* Wf2  = (const float*)d_in[16];
    const float* bf2  = (const float*)d_in[17];
    float* out = (float*)d_out;

    const int N = in_sizes[0] / 128;  // 100000
    const int E = in_sizes[1];        // 1600000

    char* w = (char*)d_ws;
    auto alloc = [&](size_t bytes) -> void* {
        void* p = (void*)w;
        w += (bytes + 255) & ~(size_t)255;
        return p;
    };
    unsigned short* Yhi    = (unsigned short*)alloc((size_t)N * 256 * 2); // spmm out hi
    unsigned short* Ylo    = (unsigned short*)alloc((size_t)N * 256 * 2); // spmm out lo
    unsigned short* Hb     = (unsigned short*)alloc((size_t)N * 256 * 2); // bf16 activations
    unsigned short* xb     = (unsigned short*)alloc((size_t)N * 128 * 2); // bf16 input copy
    int*            cnt    = (int*)alloc((size_t)N * 4);
    int*            basep  = (int*)alloc((size_t)(N + 1) * 4);
    int*            cursor = (int*)alloc((size_t)N * 4);
    int*            part   = (int*)alloc(1024);
    int2*           edges  = (int2*)alloc((size_t)E * 8);
    short* Wq1a = (short*)alloc((size_t)128 * 256 * 2 * 2);
    short* Wq2a = (short*)alloc((size_t)256 * 256 * 2 * 2);
    short* Wq1b = (short*)alloc((size_t)256 * 256 * 2 * 2);
    short* Wq2b = (short*)alloc((size_t)256 * 256 * 2 * 2);
    short* Wqf1 = (short*)alloc((size_t)256 * 256 * 2 * 2);
    short* Wqf2 = (short*)alloc((size_t)256 * 64 * 2 * 2);

    // ---- CSR build ----
    k_zero<<<(N + 255) / 256, 256, 0, stream>>>(cnt, N);
    k_hist<<<(E + 255) / 256, 256, 0, stream>>>(row, cnt, E);
    int nb = (N + 1023) / 1024;  // 98
    k_scan1<<<nb, 256, 0, stream>>>(cnt, basep, part, N);
    k_scan2<<<1, 256, 0, stream>>>(part, nb);
    k_scan3<<<(N + 255) / 256, 256, 0, stream>>>(basep, cursor, part, N, E);
    k_scatter<<<(E + 255) / 256, 256, 0, stream>>>(row, col, vals, cursor, edges, E);

    // ---- weight split+swizzle, input bf16 cast ----
    k_wprep_all<<<1216, 256, 0, stream>>>(W1a, Wq1a, W2a, Wq2a, W1b, Wq1b,
                                          W2b, Wq2b, Wf1, Wqf1, Wf2, Wqf2);
    k_cvt<<<(N * 128 / 4 + 255) / 256, 256, 0, stream>>>(x, xb, N * 128);

    const int mlp_grid  = (N + 31) / 32;
    const int spmm_grid = (N + 3) / 4;

    // ---- conv A ----
    k_spmm_bf<128><<<spmm_grid, 256, 0, stream>>>(basep, edges, xb, Yhi, Ylo, eps0, N);
    k_mlp<128, 256, true, true><<<mlp_grid, 256, 0, stream>>>(Yhi, Ylo, Wq1a, b1a, Wq2a, b2a, Hb, N);

    // ---- conv B ----
    k_spmm_bf<256><<<spmm_grid, 256, 0, stream>>>(basep, edges, Hb, Yhi, Ylo, eps1, N);
    k_mlp<256, 256, true, true><<<mlp_grid, 256, 0, stream>>>(Yhi, Ylo, Wq1b, b1b, Wq2b, b2b, Hb, N);

    // ---- head (single-plane bf16 A, exact -> 2 MFMAs in GEMM1) ----
    k_mlp<256, 64, false, false><<<mlp_grid, 256, 0, stream>>>(Hb, nullptr, Wqf1, bf1, Wqf2, bf2, out, N);
}